// Round 1
// baseline (8998.383 us; speedup 1.0000x reference)
//
#include <hip/hip_runtime.h>

// Problem constants (fixed shapes from reference)
constexpr int S   = 4096;   // sequence length
constexpr int H   = 512;    // hidden
constexpr int G3  = 1536;   // 3*H
constexpr int NWG = 32;     // scan worker workgroups; each owns H/NWG = 16 hidden idx

// ---------------------------------------------------------------------------
// Kernel A: gx[t][o] = b_ih[o] + sum_k emb[x[t]][k] * w_ih[o][k]
// 128x128 output tile per block, K-chunks of 32, fp32 VALU FMA.
// A staged natural ([row][kk], pad 36 -> aligned float4 writes, ~2-way-read ok),
// B staged transposed ([kk][col], pad 132 -> aligned float4 reads).
// ---------------------------------------------------------------------------
__global__ __launch_bounds__(256) void gemm_gx(
    const int* __restrict__ x, const float* __restrict__ emb,
    const float* __restrict__ w_ih, const float* __restrict__ b_ih,
    float* __restrict__ gx)
{
    __shared__ alignas(16) float As[128][36];
    __shared__ alignas(16) float Bs[32][132];

    const int tid  = threadIdx.x;
    const int row0 = (blockIdx.x / 12) * 128;
    const int col0 = (blockIdx.x % 12) * 128;
    const int tx   = tid & 15;   // col group
    const int ty   = tid >> 4;   // row group

    float acc[8][8] = {};

    for (int k0 = 0; k0 < H; k0 += 32) {
        // stage A (gathered emb rows) and B (w_ih rows)
        #pragma unroll
        for (int p = 0; p < 4; ++p) {
            const int rl = (tid >> 3) + 32 * p;
            const int kk = (tid & 7) * 4;
            const int xi = x[row0 + rl];
            const float4 va = *reinterpret_cast<const float4*>(
                emb + (size_t)xi * H + k0 + kk);
            *reinterpret_cast<float4*>(&As[rl][kk]) = va;

            const float4 vb = *reinterpret_cast<const float4*>(
                w_ih + (size_t)(col0 + rl) * H + k0 + kk);
            Bs[kk + 0][rl] = vb.x; Bs[kk + 1][rl] = vb.y;
            Bs[kk + 2][rl] = vb.z; Bs[kk + 3][rl] = vb.w;
        }
        __syncthreads();

        #pragma unroll
        for (int kk = 0; kk < 32; ++kk) {
            float a[8], b[8];
            #pragma unroll
            for (int q = 0; q < 4; ++q) {
                a[q]     = As[ty * 4 + q][kk];
                a[4 + q] = As[ty * 4 + 64 + q][kk];
            }
            const float4 b0 = *reinterpret_cast<const float4*>(&Bs[kk][tx * 4]);
            const float4 b1 = *reinterpret_cast<const float4*>(&Bs[kk][tx * 4 + 64]);
            b[0]=b0.x; b[1]=b0.y; b[2]=b0.z; b[3]=b0.w;
            b[4]=b1.x; b[5]=b1.y; b[6]=b1.z; b[7]=b1.w;
            #pragma unroll
            for (int ri = 0; ri < 8; ++ri)
                #pragma unroll
                for (int ci = 0; ci < 8; ++ci)
                    acc[ri][ci] = fmaf(a[ri], b[ci], acc[ri][ci]);
        }
        __syncthreads();
    }

    float bi[8];
    #pragma unroll
    for (int q = 0; q < 4; ++q) {
        bi[q]     = b_ih[col0 + tx * 4 + q];
        bi[4 + q] = b_ih[col0 + tx * 4 + 64 + q];
    }
    #pragma unroll
    for (int ri = 0; ri < 8; ++ri) {
        const int rr = row0 + ty * 4 + (ri & 3) + ((ri >> 2) << 6);
        float4 o0, o1;
        o0.x = acc[ri][0] + bi[0]; o0.y = acc[ri][1] + bi[1];
        o0.z = acc[ri][2] + bi[2]; o0.w = acc[ri][3] + bi[3];
        o1.x = acc[ri][4] + bi[4]; o1.y = acc[ri][5] + bi[5];
        o1.z = acc[ri][6] + bi[6]; o1.w = acc[ri][7] + bi[7];
        *reinterpret_cast<float4*>(gx + (size_t)rr * G3 + col0 + tx * 4)      = o0;
        *reinterpret_cast<float4*>(gx + (size_t)rr * G3 + col0 + tx * 4 + 64) = o1;
    }
}

// ---------------------------------------------------------------------------
// Kernel B: persistent GRU scan. 32 WGs x 256 threads.
// WG k owns hidden slice [16k, 16k+16). Lane-group g (16 lanes) computes the
// r/z/n dot products for hidden index i = 16k+g; W_hh slice lives in VGPRs.
// Cross-WG sync: tag-in-data 64-bit agent-scope atomics, double-buffered.
//   hbuf[(s+1)&1][i] = (tag=s+1)<<32 | f32(h_{s+1}[i])   (tags memset 0/launch)
// Safety: relaxed is OK by dataflow (store value depends on all 512 loads);
// producer can't write tag s+2 into a buffer until every WG stored tag s+1,
// which happens only after they finished reading step-s values.
// ---------------------------------------------------------------------------
__global__ __launch_bounds__(256) void gru_scan(
    const float* __restrict__ gx,
    const float* __restrict__ w_hh,
    const float* __restrict__ b_hh,
    const float* __restrict__ dec_w,
    const float* __restrict__ dec_b,
    const float* __restrict__ target,
    unsigned long long* __restrict__ hbuf,   // [2][H] (tag|value)
    float* __restrict__ out)
{
    __shared__ float h_lds[H];

    const int k   = blockIdx.x;
    const int tid = threadIdx.x;
    const int l   = tid & 15;    // lane within 16-lane group (column owner)
    const int g   = tid >> 4;    // group id 0..15
    const int i   = k * 16 + g;  // owned hidden index

    // Register-resident recurrent weights: rows i, H+i, 2H+i; cols l+16j.
    float wr[32], wz[32], wn[32];
    #pragma unroll
    for (int j = 0; j < 32; ++j) {
        const int c = l + 16 * j;
        wr[j] = w_hh[(size_t)i * H + c];
        wz[j] = w_hh[(size_t)(H + i) * H + c];
        wn[j] = w_hh[(size_t)(2 * H + i) * H + c];
    }
    const float bhr = b_hh[i], bhz = b_hh[H + i], bhn = b_hh[2 * H + i];

    // gx prefetch regs (only lane 0 of each group uses them)
    float gxr = 0.f, gxz = 0.f, gxn = 0.f;
    if (l == 0) { gxr = gx[i]; gxz = gx[H + i]; gxn = gx[2 * H + i]; }

    const int e0 = tid, e1 = tid + 256;

    for (int s = 0; s < S; ++s) {
        // --- obtain h_s into LDS ---
        if (s == 0) {
            h_lds[e0] = 0.f; h_lds[e1] = 0.f;   // h0 = zeros, no poll
        } else {
            unsigned long long* src = hbuf + (size_t)(s & 1) * H;
            unsigned long long v0 = 0, v1 = 0;
            bool d0 = false, d1 = false;
            const unsigned tg = (unsigned)s;
            while (true) {
                if (!d0) { v0 = __hip_atomic_load(src + e0, __ATOMIC_RELAXED,
                                                  __HIP_MEMORY_SCOPE_AGENT);
                           d0 = (unsigned)(v0 >> 32) == tg; }
                if (!d1) { v1 = __hip_atomic_load(src + e1, __ATOMIC_RELAXED,
                                                  __HIP_MEMORY_SCOPE_AGENT);
                           d1 = (unsigned)(v1 >> 32) == tg; }
                if (d0 && d1) break;
                __builtin_amdgcn_s_sleep(1);
            }
            h_lds[e0] = __uint_as_float((unsigned)v0);
            h_lds[e1] = __uint_as_float((unsigned)v1);
        }
        __syncthreads();

        // --- three 512-dots, split 32 cols/lane across 16 lanes ---
        float hv[32];
        #pragma unroll
        for (int j = 0; j < 32; ++j) hv[j] = h_lds[l + 16 * j];
        float ar = 0.f, az = 0.f, an = 0.f;
        #pragma unroll
        for (int j = 0; j < 32; ++j) {
            ar = fmaf(wr[j], hv[j], ar);
            az = fmaf(wz[j], hv[j], az);
            an = fmaf(wn[j], hv[j], an);
        }
        #pragma unroll
        for (int m = 8; m >= 1; m >>= 1) {   // butterfly within 16-lane group
            ar += __shfl_xor(ar, m);
            az += __shfl_xor(az, m);
            an += __shfl_xor(an, m);
        }

        if (l == 0) {
            const float r  = 1.f / (1.f + __expf(-(gxr + ar + bhr)));
            const float z  = 1.f / (1.f + __expf(-(gxz + az + bhz)));
            const float nn = tanhf(gxn + r * (an + bhn));
            const float hp = h_lds[i];
            const float hnew = (1.f - z) * nn + z * hp;
            const unsigned long long pv =
                ((unsigned long long)(unsigned)(s + 1) << 32) |
                (unsigned long long)__float_as_uint(hnew);
            __hip_atomic_store(hbuf + (size_t)((s + 1) & 1) * H + i, pv,
                               __ATOMIC_RELAXED, __HIP_MEMORY_SCOPE_AGENT);
            // prefetch next step's gx slice (hidden under next poll/compute)
            const int sn = (s + 1 < S) ? (s + 1) : s;
            gxr = gx[(size_t)sn * G3 + i];
            gxz = gx[(size_t)sn * G3 + H + i];
            gxn = gx[(size_t)sn * G3 + 2 * H + i];
        }
        __syncthreads();
    }

    // --- epilogue: WG0 gathers h_S (tag S, buffer S&1 == 0) and computes BCE ---
    if (k == 0) {
        unsigned long long* src = hbuf;  // (S & 1) == 0
        unsigned long long v0 = 0, v1 = 0;
        bool d0 = false, d1 = false;
        while (true) {
            if (!d0) { v0 = __hip_atomic_load(src + e0, __ATOMIC_RELAXED,
                                              __HIP_MEMORY_SCOPE_AGENT);
                       d0 = (unsigned)(v0 >> 32) == (unsigned)S; }
            if (!d1) { v1 = __hip_atomic_load(src + e1, __ATOMIC_RELAXED,
                                              __HIP_MEMORY_SCOPE_AGENT);
                       d1 = (unsigned)(v1 >> 32) == (unsigned)S; }
            if (d0 && d1) break;
            __builtin_amdgcn_s_sleep(1);
        }
        h_lds[e0] = __uint_as_float((unsigned)v0);
        h_lds[e1] = __uint_as_float((unsigned)v1);
        __syncthreads();

        if (tid < 64) {
            float p = 0.f;
            #pragma unroll
            for (int j = 0; j < 8; ++j)
                p = fmaf(h_lds[tid + 64 * j], dec_w[tid + 64 * j], p);
            #pragma unroll
            for (int m = 32; m >= 1; m >>= 1) p += __shfl_xor(p, m);
            if (tid == 0) {
                const float xl = p + dec_b[0];
                const float t  = target[0];
                // loss = softplus(xl) - t*xl  (stable BCE-with-logits)
                const float loss = fmaxf(xl, 0.f) - xl * t +
                                   log1pf(__expf(-fabsf(xl)));
                out[0] = loss;
            }
        }
    }
}

// ---------------------------------------------------------------------------
extern "C" void kernel_launch(void* const* d_in, const int* in_sizes, int n_in,
                              void* d_out, int out_size, void* d_ws, size_t ws_size,
                              hipStream_t stream) {
    const int*   x      = (const int*)d_in[0];
    const float* target = (const float*)d_in[1];
    const float* emb    = (const float*)d_in[2];
    const float* w_ih   = (const float*)d_in[3];
    const float* w_hh   = (const float*)d_in[4];
    const float* b_ih   = (const float*)d_in[5];
    const float* b_hh   = (const float*)d_in[6];
    const float* dec_w  = (const float*)d_in[7];
    const float* dec_b  = (const float*)d_in[8];
    float*       out    = (float*)d_out;

    float* gx = (float*)d_ws;                                   // [S][1536] = 25.2 MB
    unsigned long long* hbuf =
        (unsigned long long*)((char*)d_ws + (size_t)S * G3 * sizeof(float)); // [2][H]

    // Clear tags every launch so graph replays can't match stale tags.
    hipMemsetAsync(hbuf, 0, 2 * H * sizeof(unsigned long long), stream);

    gemm_gx<<<dim3(32 * 12), dim3(256), 0, stream>>>(x, emb, w_ih, b_ih, gx);
    gru_scan<<<dim3(NWG), dim3(256), 0, stream>>>(gx, w_hh, b_hh, dec_w, dec_b,
                                                  target, hbuf, out);
}

// Round 3
// 8089.921 us; speedup vs baseline: 1.1123x; 1.1123x over previous
//
#include <hip/hip_runtime.h>

// Problem constants (fixed shapes from reference)
constexpr int S   = 4096;   // sequence length
constexpr int H   = 512;    // hidden
constexpr int G3  = 1536;   // 3*H
constexpr int NWG = 32;     // scan worker workgroups; each owns H/NWG = 16 hidden idx

// ---------------------------------------------------------------------------
// Kernel A: gx[t][o] = b_ih[o] + sum_k emb[x[t]][k] * w_ih[o][k]
// (unchanged — passed with absmax 0.0; ~1% of runtime)
// ---------------------------------------------------------------------------
__global__ __launch_bounds__(256) void gemm_gx(
    const int* __restrict__ x, const float* __restrict__ emb,
    const float* __restrict__ w_ih, const float* __restrict__ b_ih,
    float* __restrict__ gx)
{
    __shared__ alignas(16) float As[128][36];
    __shared__ alignas(16) float Bs[32][132];

    const int tid  = threadIdx.x;
    const int row0 = (blockIdx.x / 12) * 128;
    const int col0 = (blockIdx.x % 12) * 128;
    const int tx   = tid & 15;
    const int ty   = tid >> 4;

    float acc[8][8] = {};

    for (int k0 = 0; k0 < H; k0 += 32) {
        #pragma unroll
        for (int p = 0; p < 4; ++p) {
            const int rl = (tid >> 3) + 32 * p;
            const int kk = (tid & 7) * 4;
            const int xi = x[row0 + rl];
            const float4 va = *reinterpret_cast<const float4*>(
                emb + (size_t)xi * H + k0 + kk);
            *reinterpret_cast<float4*>(&As[rl][kk]) = va;

            const float4 vb = *reinterpret_cast<const float4*>(
                w_ih + (size_t)(col0 + rl) * H + k0 + kk);
            Bs[kk + 0][rl] = vb.x; Bs[kk + 1][rl] = vb.y;
            Bs[kk + 2][rl] = vb.z; Bs[kk + 3][rl] = vb.w;
        }
        __syncthreads();

        #pragma unroll
        for (int kk = 0; kk < 32; ++kk) {
            float a[8], b[8];
            #pragma unroll
            for (int q = 0; q < 4; ++q) {
                a[q]     = As[ty * 4 + q][kk];
                a[4 + q] = As[ty * 4 + 64 + q][kk];
            }
            const float4 b0 = *reinterpret_cast<const float4*>(&Bs[kk][tx * 4]);
            const float4 b1 = *reinterpret_cast<const float4*>(&Bs[kk][tx * 4 + 64]);
            b[0]=b0.x; b[1]=b0.y; b[2]=b0.z; b[3]=b0.w;
            b[4]=b1.x; b[5]=b1.y; b[6]=b1.z; b[7]=b1.w;
            #pragma unroll
            for (int ri = 0; ri < 8; ++ri)
                #pragma unroll
                for (int ci = 0; ci < 8; ++ci)
                    acc[ri][ci] = fmaf(a[ri], b[ci], acc[ri][ci]);
        }
        __syncthreads();
    }

    float bi[8];
    #pragma unroll
    for (int q = 0; q < 4; ++q) {
        bi[q]     = b_ih[col0 + tx * 4 + q];
        bi[4 + q] = b_ih[col0 + tx * 4 + 64 + q];
    }
    #pragma unroll
    for (int ri = 0; ri < 8; ++ri) {
        const int rr = row0 + ty * 4 + (ri & 3) + ((ri >> 2) << 6);
        float4 o0, o1;
        o0.x = acc[ri][0] + bi[0]; o0.y = acc[ri][1] + bi[1];
        o0.z = acc[ri][2] + bi[2]; o0.w = acc[ri][3] + bi[3];
        o1.x = acc[ri][4] + bi[4]; o1.y = acc[ri][5] + bi[5];
        o1.z = acc[ri][6] + bi[6]; o1.w = acc[ri][7] + bi[7];
        *reinterpret_cast<float4*>(gx + (size_t)rr * G3 + col0 + tx * 4)      = o0;
        *reinterpret_cast<float4*>(gx + (size_t)rr * G3 + col0 + tx * 4 + 64) = o1;
    }
}

// ---------------------------------------------------------------------------
// Kernel B: persistent GRU scan. 32 WGs x 256 threads.
// ROUND-1-PROVEN sync semantics (tag-in-data u64, double buffer, relaxed
// agent-scope atomics, unbounded poll, two barriers/step). Changes this
// round are register/access-width only:
//   - __launch_bounds__(256,1): VGPR budget 512 -> W_hh slice stays in VGPRs
//     (round 1: VGPR_Count=80 proved the 96 floats/thread spilled to scratch,
//     re-read every step on the critical path).
//   - lane l owns columns 4l+64j+q: weights as float4[8] x3, h as float4 LDS
//     reads (ds_read_b128, 2-way bank = free) instead of 32x ds_read_b32.
//   - no s_sleep in the poll (tighter sampling of the tag line).
// ---------------------------------------------------------------------------
__global__ __launch_bounds__(256, 1) void gru_scan(
    const float* __restrict__ gx,
    const float* __restrict__ w_hh,
    const float* __restrict__ b_hh,
    const float* __restrict__ dec_w,
    const float* __restrict__ dec_b,
    const float* __restrict__ target,
    unsigned long long* __restrict__ hbuf,   // [2][H] (tag|value)
    float* __restrict__ out)
{
    __shared__ float h_lds[H];

    const int k   = blockIdx.x;
    const int tid = threadIdx.x;
    const int l   = tid & 15;    // lane within 16-lane group (column owner)
    const int g   = tid >> 4;    // group id 0..15
    const int i   = k * 16 + g;  // owned hidden index

    // Register-resident recurrent weights: rows i, H+i, 2H+i; cols 4l+64j+q.
    float4 wr[8], wz[8], wn[8];
    #pragma unroll
    for (int j = 0; j < 8; ++j) {
        const int c = 4 * l + 64 * j;
        wr[j] = *reinterpret_cast<const float4*>(w_hh + (size_t)i * H + c);
        wz[j] = *reinterpret_cast<const float4*>(w_hh + (size_t)(H + i) * H + c);
        wn[j] = *reinterpret_cast<const float4*>(w_hh + (size_t)(2 * H + i) * H + c);
    }
    const float bhr = b_hh[i], bhz = b_hh[H + i], bhn = b_hh[2 * H + i];

    // gx prefetch regs (only lane 0 of each group uses them)
    float gxr = 0.f, gxz = 0.f, gxn = 0.f;
    if (l == 0) { gxr = gx[i]; gxz = gx[H + i]; gxn = gx[2 * H + i]; }

    const int e0 = tid, e1 = tid + 256;

    for (int s = 0; s < S; ++s) {
        // --- obtain h_s into LDS ---
        if (s == 0) {
            h_lds[e0] = 0.f; h_lds[e1] = 0.f;   // h0 = zeros, no poll
        } else {
            unsigned long long* src = hbuf + (size_t)(s & 1) * H;
            unsigned long long v0 = 0, v1 = 0;
            bool d0 = false, d1 = false;
            const unsigned tg = (unsigned)s;
            while (true) {
                if (!d0) { v0 = __hip_atomic_load(src + e0, __ATOMIC_RELAXED,
                                                  __HIP_MEMORY_SCOPE_AGENT);
                           d0 = (unsigned)(v0 >> 32) == tg; }
                if (!d1) { v1 = __hip_atomic_load(src + e1, __ATOMIC_RELAXED,
                                                  __HIP_MEMORY_SCOPE_AGENT);
                           d1 = (unsigned)(v1 >> 32) == tg; }
                if (d0 && d1) break;
            }
            h_lds[e0] = __uint_as_float((unsigned)v0);
            h_lds[e1] = __uint_as_float((unsigned)v1);
        }
        __syncthreads();

        const float hp = h_lds[i];

        // --- three 512-dots: lane l covers cols 4l+64j+q via ds_read_b128 ---
        float ar = 0.f, az = 0.f, an = 0.f;
        #pragma unroll
        for (int j = 0; j < 8; ++j) {
            const float4 hv =
                *reinterpret_cast<const float4*>(&h_lds[64 * j + 4 * l]);
            ar = fmaf(wr[j].x, hv.x, fmaf(wr[j].y, hv.y,
                 fmaf(wr[j].z, hv.z, fmaf(wr[j].w, hv.w, ar))));
            az = fmaf(wz[j].x, hv.x, fmaf(wz[j].y, hv.y,
                 fmaf(wz[j].z, hv.z, fmaf(wz[j].w, hv.w, az))));
            an = fmaf(wn[j].x, hv.x, fmaf(wn[j].y, hv.y,
                 fmaf(wn[j].z, hv.z, fmaf(wn[j].w, hv.w, an))));
        }
        #pragma unroll
        for (int m = 8; m >= 1; m >>= 1) {   // butterfly within 16-lane group
            ar += __shfl_xor(ar, m);
            az += __shfl_xor(az, m);
            an += __shfl_xor(an, m);
        }

        if (l == 0) {
            const float r  = 1.f / (1.f + __expf(-(gxr + ar + bhr)));
            const float z  = 1.f / (1.f + __expf(-(gxz + az + bhz)));
            const float nn = tanhf(gxn + r * (an + bhn));
            const float hnew = (1.f - z) * nn + z * hp;
            const unsigned long long pv =
                ((unsigned long long)(unsigned)(s + 1) << 32) |
                (unsigned long long)__float_as_uint(hnew);
            __hip_atomic_store(hbuf + (size_t)((s + 1) & 1) * H + i, pv,
                               __ATOMIC_RELAXED, __HIP_MEMORY_SCOPE_AGENT);
            // prefetch next step's gx slice (hidden under next poll/compute)
            const int sn = (s + 1 < S) ? (s + 1) : s;
            gxr = gx[(size_t)sn * G3 + i];
            gxz = gx[(size_t)sn * G3 + H + i];
            gxn = gx[(size_t)sn * G3 + 2 * H + i];
        }
        __syncthreads();
    }

    // --- epilogue: WG0 gathers h_S (tag S, buffer S&1 == 0) and computes BCE ---
    if (k == 0) {
        unsigned long long* src = hbuf;  // (S & 1) == 0
        unsigned long long v0 = 0, v1 = 0;
        bool d0 = false, d1 = false;
        while (true) {
            if (!d0) { v0 = __hip_atomic_load(src + e0, __ATOMIC_RELAXED,
                                              __HIP_MEMORY_SCOPE_AGENT);
                       d0 = (unsigned)(v0 >> 32) == (unsigned)S; }
            if (!d1) { v1 = __hip_atomic_load(src + e1, __ATOMIC_RELAXED,
                                              __HIP_MEMORY_SCOPE_AGENT);
                       d1 = (unsigned)(v1 >> 32) == (unsigned)S; }
            if (d0 && d1) break;
        }
        h_lds[e0] = __uint_as_float((unsigned)v0);
        h_lds[e1] = __uint_as_float((unsigned)v1);
        __syncthreads();

        if (tid < 64) {
            float p = 0.f;
            #pragma unroll
            for (int j = 0; j < 8; ++j)
                p = fmaf(h_lds[tid + 64 * j], dec_w[tid + 64 * j], p);
            #pragma unroll
            for (int m = 32; m >= 1; m >>= 1) p += __shfl_xor(p, m);
            if (tid == 0) {
                const float xl = p + dec_b[0];
                const float t  = target[0];
                const float loss = fmaxf(xl, 0.f) - xl * t +
                                   log1pf(__expf(-fabsf(xl)));
                out[0] = loss;
            }
        }
    }
}

// ---------------------------------------------------------------------------
extern "C" void kernel_launch(void* const* d_in, const int* in_sizes, int n_in,
                              void* d_out, int out_size, void* d_ws, size_t ws_size,
                              hipStream_t stream) {
    const int*   x      = (const int*)d_in[0];
    const float* target = (const float*)d_in[1];
    const float* emb    = (const float*)d_in[2];
    const float* w_ih   = (const float*)d_in[3];
    const float* w_hh   = (const float*)d_in[4];
    const float* b_ih   = (const float*)d_in[5];
    const float* b_hh   = (const float*)d_in[6];
    const float* dec_w  = (const float*)d_in[7];
    const float* dec_b  = (const float*)d_in[8];
    float*       out    = (float*)d_out;

    float* gx = (float*)d_ws;                                   // [S][1536] = 25.2 MB
    unsigned long long* hbuf =
        (unsigned long long*)((char*)d_ws + (size_t)S * G3 * sizeof(float)); // [2][H]

    // Clear tags every launch so graph replays can't match stale tags.
    hipMemsetAsync(hbuf, 0, 2 * H * sizeof(unsigned long long), stream);

    gemm_gx<<<dim3(32 * 12), dim3(256), 0, stream>>>(x, emb, w_ih, b_ih, gx);
    gru_scan<<<dim3(NWG), dim3(256), 0, stream>>>(gx, w_hh, b_hh, dec_w, dec_b,
                                                  target, hbuf, out);
}